// Round 10
// baseline (85.914 us; speedup 1.0000x reference)
//
#include <hip/hip_runtime.h>
#include <math.h>

#define BB 2
#define C_IN 32
#define HH 64
#define WW 64
#define J (HH*WW)        // 4096
#define HID 64
#define C_OUT 32
#define S 256
#define TN 128           // table knots per (b,h)
#define JT 32            // j's per eval block
#define GRID 256

// gelu(x) ~= x * sigmoid(A*x + B*x^3)  (tanh-form gelu, exp2 domain)
#define GELU_A 2.3022043f
#define GELU_B 0.10294306f

union SharedU {
    float us[4 * 66];               // phase 2: u[b,:,h] in 4 padded s-quarters
    struct {
        float Tl[HID][TN + 4];      // phase 3: row stride 132 floats, 16B-aligned
        float G[JT][HID + 1];       // phase 3: gathered F values, padded
    } e;
};                                   // 42112 B

// sense-reversing device-scope grid barrier: bar[0]=count, bar[1]=generation.
// Leaves count==0 after each use -> safe across graph replays.
__device__ __forceinline__ void grid_barrier(unsigned* bar, unsigned nblk) {
    __syncthreads();
    if (threadIdx.x == 0) {
        __threadfence();                               // device-scope visibility
        unsigned gen = __hip_atomic_load(bar + 1, __ATOMIC_RELAXED,
                                         __HIP_MEMORY_SCOPE_AGENT);
        unsigned prev = __hip_atomic_fetch_add(bar, 1u, __ATOMIC_ACQ_REL,
                                               __HIP_MEMORY_SCOPE_AGENT);
        if (prev == nblk - 1u) {
            __hip_atomic_store(bar, 0u, __ATOMIC_RELAXED,
                               __HIP_MEMORY_SCOPE_AGENT);
            __hip_atomic_fetch_add(bar + 1, 1u, __ATOMIC_RELEASE,
                                   __HIP_MEMORY_SCOPE_AGENT);
        } else {
            while (__hip_atomic_load(bar + 1, __ATOMIC_ACQUIRE,
                                     __HIP_MEMORY_SCOPE_AGENT) == gen) {
                __builtin_amdgcn_s_sleep(2);
            }
        }
    }
    __syncthreads();
}

// ---------- phase 1: ut[b,h,s] (transposed) ; wave-uniform idx ----------
__device__ __forceinline__ void phase1(int blk, int tid,
    const float* __restrict__ v, const int* __restrict__ indices,
    const float* __restrict__ W1, const float* __restrict__ b1,
    float* __restrict__ ut)
{
    int slot = blk * 2 + (tid >> 6);     // [0, 512) for tid < 128
    if (tid >= 128) return;
    int b = slot >> 8;
    int s = slot & 255;
    int h = tid & 63;
    int idx = indices[s];
    float sx = (float)(idx & (WW - 1)) * (1.0f / (WW - 1));
    float sy = (float)(idx >> 6)       * (1.0f / (HH - 1));
    float acc = b1[h] - sx * W1[h] - sy * W1[HID + h];
    const float* vb = v + (size_t)b * C_IN * J + idx;
    #pragma unroll
    for (int c = 0; c < C_IN; ++c) {
        acc = __builtin_fmaf(vb[c * J], W1[(2 + c) * HID + h], acc);
    }
    ut[((size_t)b * HID + h) * S + s] = acc;   // contiguous per (b,h)
}

// ---------- phase 2: T[b,h,n] = sum_s gelu(c_n + ut[b,h,s]) ----------
__device__ __forceinline__ void phase2(int blk, int tid, SharedU& sm,
    const float* __restrict__ ut, const float* __restrict__ W1,
    float* __restrict__ T)
{
    int b     = blk >> 7;            // 0..1
    int q     = blk & 127;
    int h     = q >> 1;              // 0..63
    int halfk = q & 1;               // which 64 knots
    // coalesced row read into padded quarters
    sm.us[(tid >> 6) * 66 + (tid & 63)] = ut[((size_t)b * HID + h) * S + tid];
    __syncthreads();

    float w0 = W1[h], w1 = W1[HID + h];
    float c0 = fminf(w0, 0.0f) + fminf(w1, 0.0f);
    float c1 = fmaxf(w0, 0.0f) + fmaxf(w1, 0.0f);
    float dc = fmaxf(c1 - c0, 1e-6f) * (1.0f / (TN - 1));
    int n  = halfk * 64 + (tid >> 2);    // knot index
    int sq = tid & 3;                    // s-quarter
    float cn = c0 + (float)n * dc;

    const float* usp = &sm.us[sq * 66];
    float acc = 0.0f;
    #pragma unroll 4
    for (int s = 0; s < 64; ++s) {
        float x = cn + usp[s];
        float p = __builtin_fmaf(-GELU_B, x * x, -GELU_A);
        float e = __builtin_amdgcn_exp2f(p * x);
        acc = __builtin_fmaf(x, __builtin_amdgcn_rcpf(e + 1.0f), acc);
    }
    acc += __shfl_xor(acc, 1);           // combine 4 s-quarters
    acc += __shfl_xor(acc, 2);
    if (sq == 0)
        T[((size_t)b * HID + h) * TN + n] = acc;
    __syncthreads();                     // us reads done before union reuse
}

// ---------- phase 3: interp + W2 epilogue ----------
__device__ __forceinline__ void phase3(int blk, int tid, SharedU& sm,
    const float* __restrict__ T, const float* __restrict__ W1,
    const float* __restrict__ W2, const float* __restrict__ b2,
    float* __restrict__ out)
{
    int b  = blk >> 7;
    int j0 = (blk & 127) * JT;

    const float4* Tb4 = (const float4*)(T + (size_t)b * HID * TN);
    #pragma unroll
    for (int k = tid; k < HID * TN / 4; k += 256) {   // 8 iters
        float4 vv = Tb4[k];
        int h = k >> 5;                  // 32 float4 per table row
        int n = (k & 31) * 4;
        *(float4*)&sm.e.Tl[h][n] = vv;
    }
    __syncthreads();

    int jl = tid & 31;
    int j  = j0 + jl;
    float xj = (float)(j & (WW - 1)) * (1.0f / (WW - 1));
    float yj = (float)(j >> 6)       * (1.0f / (HH - 1));
    #pragma unroll
    for (int k = 0; k < 8; ++k) {
        int h = (tid >> 5) + k * 8;
        float w0 = W1[h], w1 = W1[HID + h];
        float c0 = fminf(w0, 0.0f) + fminf(w1, 0.0f);
        float c1 = fmaxf(w0, 0.0f) + fmaxf(w1, 0.0f);
        float inv = (float)(TN - 1) / fmaxf(c1 - c0, 1e-6f);
        float t  = (xj * w0 + yj * w1 - c0) * inv;
        int i = (int)t;
        i = max(0, min(TN - 2, i));
        float f = t - (float)i;
        float t0 = sm.e.Tl[h][i], t1 = sm.e.Tl[h][i + 1];
        sm.e.G[jl][h] = __builtin_fmaf(f, t1 - t0, t0);
    }
    __syncthreads();

    int jj = tid & 31;
    int cb = tid >> 5;                   // 0..7
    #pragma unroll
    for (int qq = 0; qq < 4; ++qq) {
        int co = cb + 8 * qq;
        float sum = 0.0f;
        #pragma unroll
        for (int h = 0; h < HID; ++h)
            sum = __builtin_fmaf(sm.e.G[jj][h], W2[h * C_OUT + co], sum);
        out[(size_t)b * C_OUT * J + (size_t)co * J + j0 + jj] = sum * (1.0f / S) + b2[co];
    }
}

// ---------- fused kernel with hand-rolled grid barrier ----------
__global__ __launch_bounds__(256) void nystrom_fused(
    const float* __restrict__ v, const int* __restrict__ indices,
    const float* __restrict__ W1, const float* __restrict__ b1,
    const float* __restrict__ W2, const float* __restrict__ b2,
    float* __restrict__ ut, float* __restrict__ T, unsigned* __restrict__ bar,
    float* __restrict__ out)
{
    __shared__ SharedU sm;
    int tid = threadIdx.x;
    int blk = blockIdx.x;

    phase1(blk, tid, v, indices, W1, b1, ut);
    grid_barrier(bar, GRID);
    phase2(blk, tid, sm, ut, W1, T);
    grid_barrier(bar, GRID);
    phase3(blk, tid, sm, T, W1, W2, b2, out);
}

// ---------- fallback: R9's proven 3-kernel pipeline ----------
__global__ __launch_bounds__(64) void k_prep(
    const float* __restrict__ v, const int* __restrict__ indices,
    const float* __restrict__ W1, const float* __restrict__ b1,
    float* __restrict__ ut)
{
    int bs  = blockIdx.x;
    int b   = bs >> 8;
    int s   = bs & 255;
    int h   = threadIdx.x;
    int idx = indices[s];
    float sx = (float)(idx & (WW - 1)) * (1.0f / (WW - 1));
    float sy = (float)(idx >> 6)       * (1.0f / (HH - 1));
    float acc = b1[h] - sx * W1[h] - sy * W1[HID + h];
    const float* vb = v + (size_t)b * C_IN * J + idx;
    #pragma unroll
    for (int c = 0; c < C_IN; ++c) {
        acc = __builtin_fmaf(vb[c * J], W1[(2 + c) * HID + h], acc);
    }
    ut[((size_t)b * HID + h) * S + s] = acc;
}

__global__ __launch_bounds__(256) void k_table(
    const float* __restrict__ ut, const float* __restrict__ W1,
    float* __restrict__ T)
{
    __shared__ SharedU sm;
    phase2(blockIdx.x, threadIdx.x, sm, ut, W1, T);
}

__global__ __launch_bounds__(256) void k_eval(
    const float* __restrict__ T, const float* __restrict__ W1,
    const float* __restrict__ W2, const float* __restrict__ b2,
    float* __restrict__ out)
{
    __shared__ SharedU sm;
    phase3(blockIdx.x, threadIdx.x, sm, T, W1, W2, b2, out);
}

extern "C" void kernel_launch(void* const* d_in, const int* in_sizes, int n_in,
                              void* d_out, int out_size, void* d_ws, size_t ws_size,
                              hipStream_t stream) {
    const float* v       = (const float*)d_in[0];
    const int*   indices = (const int*)  d_in[1];
    const float* W1      = (const float*)d_in[2];
    const float* b1      = (const float*)d_in[3];
    const float* W2      = (const float*)d_in[4];
    const float* b2      = (const float*)d_in[5];
    float* out = (float*)d_out;
    float*    ut  = (float*)d_ws;                         // 128 KB
    float*    T   = (float*)d_ws + (size_t)BB * HID * S;  //  64 KB
    unsigned* bar = (unsigned*)((char*)d_ws + (size_t)BB * HID * S * 4
                                            + (size_t)BB * HID * TN * 4);

    hipMemsetAsync(bar, 0, 32, stream);   // count/gen start clean every call

    void* args[] = { (void*)&v, (void*)&indices, (void*)&W1, (void*)&b1,
                     (void*)&W2, (void*)&b2, (void*)&ut, (void*)&T,
                     (void*)&bar, (void*)&out };
    hipError_t err = hipLaunchCooperativeKernel((const void*)nystrom_fused,
                                                dim3(GRID), dim3(256),
                                                args, 0, stream);
    if (err != hipSuccess) {
        hipLaunchKernelGGL(k_prep,  dim3(BB * S), dim3(64),  0, stream,
                           v, indices, W1, b1, ut);
        hipLaunchKernelGGL(k_table, dim3(GRID),   dim3(256), 0, stream,
                           ut, W1, T);
        hipLaunchKernelGGL(k_eval,  dim3(GRID),   dim3(256), 0, stream,
                           T, W1, W2, b2, out);
    }
}

// Round 11
// 17.370 us; speedup vs baseline: 4.9460x; 4.9460x over previous
//
#include <hip/hip_runtime.h>
#include <math.h>

#define BB 2
#define C_IN 32
#define HH 64
#define WW 64
#define J (HH*WW)        // 4096
#define HID 64
#define C_OUT 32
#define S 256
#define TN 128           // table knots per (b,h)
#define JT 8             // j's per eval block
#define GSTR 68          // G row stride: banks (jl*4+h)%32 all-distinct on write

// gelu(x) ~= x * sigmoid(A*x + B*x^3)  (tanh-form gelu, exp2 domain)
#define GELU_A 2.3022043f
#define GELU_B 0.10294306f

// ---------- kernel 0: ut[b,h,s] = b1 - sx*w0 - sy*w1 + vp[b,idx_s]@W1[2:] ----------
// one block per (b,s): idx is wave-uniform -> scalar-broadcast v loads.  (R9 verbatim)
__global__ __launch_bounds__(64) void k_prep(
    const float* __restrict__ v, const int* __restrict__ indices,
    const float* __restrict__ W1, const float* __restrict__ b1,
    float* __restrict__ ut)
{
    int bs  = blockIdx.x;            // 0..B*S-1
    int b   = bs >> 8;
    int s   = bs & 255;
    int h   = threadIdx.x;           // 0..63
    int idx = indices[s];
    float sx = (float)(idx & (WW - 1)) * (1.0f / (WW - 1));
    float sy = (float)(idx >> 6)       * (1.0f / (HH - 1));
    float acc = b1[h] - sx * W1[h] - sy * W1[HID + h];
    const float* vb = v + (size_t)b * C_IN * J + idx;
    #pragma unroll
    for (int c = 0; c < C_IN; ++c) {
        acc = __builtin_fmaf(vb[c * J], W1[(2 + c) * HID + h], acc);
    }
    ut[((size_t)b * HID + h) * S + s] = acc;   // transposed: contiguous per (b,h)
}

// ---------- kernel A: T[b,h,n] = sum_s gelu(c_n + ut[b,h,s]) ----------
// 1024 blocks = (b, h, 16-knot group); 16 threads/knot x 16 s each.  (R9 verbatim)
__global__ __launch_bounds__(256) void k_table(
    const float* __restrict__ ut, const float* __restrict__ W1,
    float* __restrict__ T)
{
    __shared__ float us[16 * 20];        // 16 padded s-groups of 16 (stride 20: float4-aligned)
    int tid = threadIdx.x;
    int blk = blockIdx.x;                // 0..1023
    int b   = blk >> 9;                  // 0..1
    int h   = (blk >> 3) & 63;
    int ng  = blk & 7;                   // knot group (16 knots)

    if (tid < 64) {
        const float4* row4 = (const float4*)(ut + ((size_t)b * HID + h) * S);
        float4 vv = row4[tid];
        *(float4*)&us[(tid >> 2) * 20 + (tid & 3) * 4] = vv;
    }
    __syncthreads();

    float w0 = W1[h], w1 = W1[HID + h];
    float c0 = fminf(w0, 0.0f) + fminf(w1, 0.0f);
    float c1 = fmaxf(w0, 0.0f) + fmaxf(w1, 0.0f);
    float dc = fmaxf(c1 - c0, 1e-6f) * (1.0f / (TN - 1));
    int n  = ng * 16 + (tid >> 4);       // knot index
    int sg = tid & 15;                   // s-group
    float cn = c0 + (float)n * dc;

    const float* usp = &us[sg * 20];
    float acc = 0.0f;
    #pragma unroll
    for (int s = 0; s < 16; ++s) {
        float x = cn + usp[s];
        float p = __builtin_fmaf(-GELU_B, x * x, -GELU_A);
        float e = __builtin_amdgcn_exp2f(p * x);
        acc = __builtin_fmaf(x, __builtin_amdgcn_rcpf(e + 1.0f), acc);
    }
    acc += __shfl_xor(acc, 1);           // combine 16 s-groups
    acc += __shfl_xor(acc, 2);
    acc += __shfl_xor(acc, 4);
    acc += __shfl_xor(acc, 8);
    if (sg == 0)
        T[((size_t)b * HID + h) * TN + n] = acc;
}

// ---------- kernel B: interp + W2 epilogue, no LDS table ----------
// grid 1024 = (b, 8-j tile); T gathered directly from L1/L2.
__global__ __launch_bounds__(256) void k_eval(
    const float* __restrict__ T, const float* __restrict__ W1,
    const float* __restrict__ W2, const float* __restrict__ b2,
    float* __restrict__ out)
{
    __shared__ float G[JT][GSTR];        // 2.2 KB
    int tid = threadIdx.x;
    int blk = blockIdx.x;                // 0..1023
    int b   = blk >> 9;
    int j0  = (blk & 511) * JT;

    int jl = tid & 7;
    int j  = j0 + jl;
    float xj = (float)(j & (WW - 1)) * (1.0f / (WW - 1));
    float yj = (float)(j >> 6)       * (1.0f / (HH - 1));

    const float* Tb = T + (size_t)b * HID * TN;
    #pragma unroll
    for (int k = 0; k < 2; ++k) {
        int h = (tid >> 3) + k * 32;     // each thread: 2 h's
        float w0 = W1[h], w1 = W1[HID + h];
        float c0 = fminf(w0, 0.0f) + fminf(w1, 0.0f);
        float c1 = fmaxf(w0, 0.0f) + fmaxf(w1, 0.0f);
        float inv = (float)(TN - 1) / fmaxf(c1 - c0, 1e-6f);
        float t  = (xj * w0 + yj * w1 - c0) * inv;
        int i = (int)t;
        i = max(0, min(TN - 2, i));
        float f = t - (float)i;
        const float* Th = Tb + h * TN;
        float t0 = Th[i], t1 = Th[i + 1];          // L1-resident gathers
        G[jl][h] = __builtin_fmaf(f, t1 - t0, t0);
    }
    __syncthreads();

    // epilogue: one output per thread: (jl = tid&7, co = tid>>3)
    int co = tid >> 3;
    float sum = 0.0f;
    #pragma unroll
    for (int h = 0; h < HID; ++h)
        sum = __builtin_fmaf(G[jl][h], W2[h * C_OUT + co], sum);
    out[(size_t)b * C_OUT * J + (size_t)co * J + j0 + jl] = sum * (1.0f / S) + b2[co];
}

extern "C" void kernel_launch(void* const* d_in, const int* in_sizes, int n_in,
                              void* d_out, int out_size, void* d_ws, size_t ws_size,
                              hipStream_t stream) {
    const float* v       = (const float*)d_in[0];
    const int*   indices = (const int*)  d_in[1];
    const float* W1      = (const float*)d_in[2];
    const float* b1      = (const float*)d_in[3];
    const float* W2      = (const float*)d_in[4];
    const float* b2      = (const float*)d_in[5];
    float* out = (float*)d_out;
    float* ut  = (float*)d_ws;                         // B*HID*S*4  = 128 KB
    float* T   = (float*)d_ws + (size_t)BB * HID * S;  // B*HID*TN*4 =  64 KB

    hipLaunchKernelGGL(k_prep,  dim3(BB * S), dim3(64),  0, stream,
                       v, indices, W1, b1, ut);
    hipLaunchKernelGGL(k_table, dim3(1024),   dim3(256), 0, stream,
                       ut, W1, T);
    hipLaunchKernelGGL(k_eval,  dim3(1024),   dim3(256), 0, stream,
                       T, W1, W2, b2, out);
}

// Round 12
// 16.779 us; speedup vs baseline: 5.1203x; 1.0352x over previous
//
#include <hip/hip_runtime.h>
#include <math.h>

#define BB 2
#define C_IN 32
#define HH 64
#define WW 64
#define J (HH*WW)        // 4096
#define HID 64
#define C_OUT 32
#define S 256
#define TN 64            // table knots per (b,h)
#define JT 8             // j's per eval block
#define GSTR 68          // G row stride

// gelu(x) ~= x * sigmoid(A*x + B*x^3)  (tanh-form gelu, exp2 domain)
#define GELU_A 2.3022043f
#define GELU_B 0.10294306f

// ---------- kernel 0: ut[b,h,s] ; c-loop split across 2 waves ----------
__global__ __launch_bounds__(128) void k_prep(
    const float* __restrict__ v, const int* __restrict__ indices,
    const float* __restrict__ W1, const float* __restrict__ b1,
    float* __restrict__ ut)
{
    __shared__ float part[64];
    int bs = blockIdx.x;             // 0..B*S-1
    int b  = bs >> 8;
    int s  = bs & 255;
    int h  = threadIdx.x & 63;
    int wv = threadIdx.x >> 6;       // 0 or 1
    int idx = indices[s];            // uniform -> scalar loads
    const float* vb = v + (size_t)b * C_IN * J + idx;

    float acc = 0.0f;
    #pragma unroll
    for (int c = 0; c < 16; ++c) {
        int cc = wv * 16 + c;
        acc = __builtin_fmaf(vb[cc * J], W1[(2 + cc) * HID + h], acc);
    }
    if (wv) part[h] = acc;
    __syncthreads();
    if (!wv) {
        float sx = (float)(idx & (WW - 1)) * (1.0f / (WW - 1));
        float sy = (float)(idx >> 6)       * (1.0f / (HH - 1));
        acc += part[h] + b1[h] - sx * W1[h] - sy * W1[HID + h];
        ut[((size_t)b * HID + h) * S + s] = acc;   // contiguous per (b,h)
    }
}

// ---------- kernel A: T[b,h,n] = sum_s gelu(c_n + ut[b,h,s]) ----------
// 512 blocks = (b, h, 16-knot group); 16 threads/knot x 16 s each.
__global__ __launch_bounds__(256) void k_table(
    const float* __restrict__ ut, const float* __restrict__ W1,
    float* __restrict__ T)
{
    __shared__ float us[16 * 20];        // 16 padded s-groups of 16
    int tid = threadIdx.x;
    int blk = blockIdx.x;                // 0..511
    int b   = blk >> 8;                  // 0..1
    int h   = (blk >> 2) & 63;
    int ng  = blk & 3;                   // knot group (16 knots)

    if (tid < 64) {
        const float4* row4 = (const float4*)(ut + ((size_t)b * HID + h) * S);
        float4 vv = row4[tid];
        *(float4*)&us[(tid >> 2) * 20 + (tid & 3) * 4] = vv;
    }
    __syncthreads();

    float w0 = W1[h], w1 = W1[HID + h];
    float c0 = fminf(w0, 0.0f) + fminf(w1, 0.0f);
    float c1 = fmaxf(w0, 0.0f) + fmaxf(w1, 0.0f);
    float dc = fmaxf(c1 - c0, 1e-6f) * (1.0f / (TN - 1));
    int n  = ng * 16 + (tid >> 4);       // knot index 0..63
    int sg = tid & 15;                   // s-group
    float cn = c0 + (float)n * dc;

    const float* usp = &us[sg * 20];
    float acc = 0.0f;
    #pragma unroll
    for (int s = 0; s < 16; ++s) {
        float x = cn + usp[s];
        float p = __builtin_fmaf(-GELU_B, x * x, -GELU_A);
        float e = __builtin_amdgcn_exp2f(p * x);
        acc = __builtin_fmaf(x, __builtin_amdgcn_rcpf(e + 1.0f), acc);
    }
    acc += __shfl_xor(acc, 1);           // combine 16 s-groups
    acc += __shfl_xor(acc, 2);
    acc += __shfl_xor(acc, 4);
    acc += __shfl_xor(acc, 8);
    if (sg == 0)
        T[((size_t)b * HID + h) * TN + n] = acc;
}

// ---------- kernel B: interp + W2 epilogue, T gathered from L1 ----------
__global__ __launch_bounds__(256) void k_eval(
    const float* __restrict__ T, const float* __restrict__ W1,
    const float* __restrict__ W2, const float* __restrict__ b2,
    float* __restrict__ out)
{
    __shared__ float G[JT][GSTR];        // 2.2 KB
    int tid = threadIdx.x;
    int blk = blockIdx.x;                // 0..1023
    int b   = blk >> 9;
    int j0  = (blk & 511) * JT;

    int jl = tid & 7;
    int j  = j0 + jl;
    float xj = (float)(j & (WW - 1)) * (1.0f / (WW - 1));
    float yj = (float)(j >> 6)       * (1.0f / (HH - 1));

    const float* Tb = T + (size_t)b * HID * TN;
    #pragma unroll
    for (int k = 0; k < 2; ++k) {
        int h = (tid >> 3) + k * 32;     // each thread: 2 h's
        float w0 = W1[h], w1 = W1[HID + h];
        float c0 = fminf(w0, 0.0f) + fminf(w1, 0.0f);
        float c1 = fmaxf(w0, 0.0f) + fmaxf(w1, 0.0f);
        float inv = (float)(TN - 1) / fmaxf(c1 - c0, 1e-6f);
        float t  = (xj * w0 + yj * w1 - c0) * inv;
        int i = (int)t;
        i = max(0, min(TN - 2, i));
        float f = t - (float)i;
        const float* Th = Tb + h * TN;
        float t0 = Th[i], t1 = Th[i + 1];          // L1-resident gathers
        G[jl][h] = __builtin_fmaf(f, t1 - t0, t0);
    }
    __syncthreads();

    int co = tid >> 3;                   // one output per thread
    float sum = 0.0f;
    #pragma unroll
    for (int h = 0; h < HID; ++h)
        sum = __builtin_fmaf(G[jl][h], W2[h * C_OUT + co], sum);
    out[(size_t)b * C_OUT * J + (size_t)co * J + j0 + jl] = sum * (1.0f / S) + b2[co];
}

extern "C" void kernel_launch(void* const* d_in, const int* in_sizes, int n_in,
                              void* d_out, int out_size, void* d_ws, size_t ws_size,
                              hipStream_t stream) {
    const float* v       = (const float*)d_in[0];
    const int*   indices = (const int*)  d_in[1];
    const float* W1      = (const float*)d_in[2];
    const float* b1      = (const float*)d_in[3];
    const float* W2      = (const float*)d_in[4];
    const float* b2      = (const float*)d_in[5];
    float* out = (float*)d_out;
    float* ut  = (float*)d_ws;                         // B*HID*S*4  = 128 KB
    float* T   = (float*)d_ws + (size_t)BB * HID * S;  // B*HID*TN*4 =  32 KB

    hipLaunchKernelGGL(k_prep,  dim3(BB * S), dim3(128), 0, stream,
                       v, indices, W1, b1, ut);
    hipLaunchKernelGGL(k_table, dim3(512),    dim3(256), 0, stream,
                       ut, W1, T);
    hipLaunchKernelGGL(k_eval,  dim3(1024),   dim3(256), 0, stream,
                       T, W1, W2, b2, out);
}

// Round 13
// 16.769 us; speedup vs baseline: 5.1233x; 1.0006x over previous
//
#include <hip/hip_runtime.h>
#include <math.h>

#define BB 2
#define C_IN 32
#define HH 64
#define WW 64
#define J (HH*WW)        // 4096
#define HID 64
#define C_OUT 32
#define S 256
#define TN 64            // table knots per (b,h)
#define JT 8             // j's per eval block
#define GSTR 68          // G row stride

// gelu(x) ~= x * sigmoid(A*x + B*x^3)  (tanh-form gelu, exp2 domain)
#define GELU_A 2.3022043f
#define GELU_B 0.10294306f

// ---------- kernel A: fused prep+table, one block per (b,h) ----------
// phase A: thread=s computes u[b,s,h] (32 v-gathers, W1 column is
// block-uniform -> scalar loads). phase B: R12's knot-sum structure.
__global__ __launch_bounds__(256) void k_table(
    const float* __restrict__ v, const int* __restrict__ indices,
    const float* __restrict__ W1, const float* __restrict__ b1,
    float* __restrict__ T)
{
    __shared__ float us[4 * 66];         // 4 padded s-quarters of 64 (stride 66)
    int tid = threadIdx.x;
    int blk = blockIdx.x;                // 0..127
    int b   = blk >> 6;                  // 0..1
    int h   = blk & 63;

    float w0 = W1[h], w1 = W1[HID + h];  // block-uniform
    float bh = b1[h];

    // --- phase A: u[b,s,h] for s = tid ---
    {
        int s   = tid;
        int idx = indices[s];
        float sx = (float)(idx & (WW - 1)) * (1.0f / (WW - 1));
        float sy = (float)(idx >> 6)       * (1.0f / (HH - 1));
        float acc = bh - sx * w0 - sy * w1;
        const float* vb = v + (size_t)b * C_IN * J + idx;
        #pragma unroll
        for (int c = 0; c < C_IN; ++c) {
            acc = __builtin_fmaf(vb[c * J], W1[(2 + c) * HID + h], acc);
        }
        us[(s >> 6) * 66 + (s & 63)] = acc;
    }
    __syncthreads();

    // --- phase B: 64 knots x 4 s-quarters (64 gelus/thread) ---
    float c0 = fminf(w0, 0.0f) + fminf(w1, 0.0f);
    float c1 = fmaxf(w0, 0.0f) + fmaxf(w1, 0.0f);
    float dc = fmaxf(c1 - c0, 1e-6f) * (1.0f / (TN - 1));
    int n  = tid >> 2;                   // knot index 0..63
    int sq = tid & 3;                    // s-quarter
    float cn = c0 + (float)n * dc;

    const float* usp = &us[sq * 66];
    float acc = 0.0f;
    #pragma unroll 4
    for (int s = 0; s < 64; ++s) {
        float x = cn + usp[s];           // 4 distinct banks, broadcast in-group
        float p = __builtin_fmaf(-GELU_B, x * x, -GELU_A);
        float e = __builtin_amdgcn_exp2f(p * x);
        acc = __builtin_fmaf(x, __builtin_amdgcn_rcpf(e + 1.0f), acc);
    }
    acc += __shfl_xor(acc, 1);           // combine 4 s-quarters
    acc += __shfl_xor(acc, 2);
    if (sq == 0)
        T[((size_t)b * HID + h) * TN + n] = acc;
}

// ---------- kernel B: interp + W2 epilogue (R12 verbatim) ----------
__global__ __launch_bounds__(256) void k_eval(
    const float* __restrict__ T, const float* __restrict__ W1,
    const float* __restrict__ W2, const float* __restrict__ b2,
    float* __restrict__ out)
{
    __shared__ float G[JT][GSTR];        // 2.2 KB
    int tid = threadIdx.x;
    int blk = blockIdx.x;                // 0..1023
    int b   = blk >> 9;
    int j0  = (blk & 511) * JT;

    int jl = tid & 7;
    int j  = j0 + jl;
    float xj = (float)(j & (WW - 1)) * (1.0f / (WW - 1));
    float yj = (float)(j >> 6)       * (1.0f / (HH - 1));

    const float* Tb = T + (size_t)b * HID * TN;
    #pragma unroll
    for (int k = 0; k < 2; ++k) {
        int h = (tid >> 3) + k * 32;     // each thread: 2 h's
        float w0 = W1[h], w1 = W1[HID + h];
        float c0 = fminf(w0, 0.0f) + fminf(w1, 0.0f);
        float c1 = fmaxf(w0, 0.0f) + fmaxf(w1, 0.0f);
        float inv = (float)(TN - 1) / fmaxf(c1 - c0, 1e-6f);
        float t  = (xj * w0 + yj * w1 - c0) * inv;
        int i = (int)t;
        i = max(0, min(TN - 2, i));
        float f = t - (float)i;
        const float* Th = Tb + h * TN;
        float t0 = Th[i], t1 = Th[i + 1];          // L1-resident gathers
        G[jl][h] = __builtin_fmaf(f, t1 - t0, t0);
    }
    __syncthreads();

    int co = tid >> 3;                   // one output per thread
    float sum = 0.0f;
    #pragma unroll
    for (int h = 0; h < HID; ++h)
        sum = __builtin_fmaf(G[jl][h], W2[h * C_OUT + co], sum);
    out[(size_t)b * C_OUT * J + (size_t)co * J + j0 + jl] = sum * (1.0f / S) + b2[co];
}

extern "C" void kernel_launch(void* const* d_in, const int* in_sizes, int n_in,
                              void* d_out, int out_size, void* d_ws, size_t ws_size,
                              hipStream_t stream) {
    const float* v       = (const float*)d_in[0];
    const int*   indices = (const int*)  d_in[1];
    const float* W1      = (const float*)d_in[2];
    const float* b1      = (const float*)d_in[3];
    const float* W2      = (const float*)d_in[4];
    const float* b2      = (const float*)d_in[5];
    float* out = (float*)d_out;
    float* T   = (float*)d_ws;           // B*HID*TN*4 = 32 KB

    hipLaunchKernelGGL(k_table, dim3(BB * HID), dim3(256), 0, stream,
                       v, indices, W1, b1, T);
    hipLaunchKernelGGL(k_eval,  dim3(1024),     dim3(256), 0, stream,
                       T, W1, W2, b2, out);
}